// Round 4
// baseline (395.779 us; speedup 1.0000x reference)
//
#include <hip/hip_runtime.h>
#include <math.h>

// Problem constants
#define BB 2
#define TT 2048
#define CC 2048
#define HH 16
#define HKK 4
#define HD 128
#define MM (BB*TT)          // 4096 rows

typedef short bf16x8 __attribute__((ext_vector_type(8)));
typedef float f32x4 __attribute__((ext_vector_type(4)));
typedef float f32x16 __attribute__((ext_vector_type(16)));
typedef int   i32x4 __attribute__((ext_vector_type(4)));

#define GLOBAL_AS(p) ((const __attribute__((address_space(1))) void*)(p))
#define LDS_AS(p)    ((__attribute__((address_space(3))) void*)(p))

__device__ __forceinline__ unsigned short f2bf(float f) {
    unsigned u = __float_as_uint(f);
    u += 0x7fff + ((u >> 16) & 1);          // round-to-nearest-even
    return (unsigned short)(u >> 16);
}
__device__ __forceinline__ float bf2f(unsigned short h) {
    return __uint_as_float(((unsigned)h) << 16);
}

// softmax scale 1/sqrt(128) * log2(e), folded into q at projection time
#define QSCALE (0.08838834764831845f * 1.44269504088896340736f)

// ---------------------------------------------------------------------------
// cast x (f32 -> bf16), 8 elements/thread
// ---------------------------------------------------------------------------
__global__ __launch_bounds__(256) void cast_x_kernel(
    const float* __restrict__ x, unsigned short* __restrict__ xb)
{
    size_t i = ((size_t)blockIdx.x * 256 + threadIdx.x) * 8;
    float4 a = *(const float4*)&x[i];
    float4 b = *(const float4*)&x[i + 4];
    uint4 r;
    r.x = f2bf(a.x) | ((unsigned)f2bf(a.y) << 16);
    r.y = f2bf(a.z) | ((unsigned)f2bf(a.w) << 16);
    r.z = f2bf(b.x) | ((unsigned)f2bf(b.y) << 16);
    r.w = f2bf(b.z) | ((unsigned)f2bf(b.w) << 16);
    *(uint4*)&xb[i] = r;
}

// ---------------------------------------------------------------------------
// Weight transpose+cast: W[K][N] f32 -> Wt[N][K] bf16.
// ---------------------------------------------------------------------------
__global__ __launch_bounds__(256) void wtrans_kernel(
    const float* __restrict__ Wq, const float* __restrict__ Wk,
    const float* __restrict__ Wv, const float* __restrict__ Wo,
    unsigned short* __restrict__ Wt, unsigned short* __restrict__ Wot)
{
    __shared__ float tile[64][65];
    int z = blockIdx.z;
    const float* src; unsigned short* dst; int ldW, nmax, noff;
    if (z == 0)      { src = Wq; dst = Wt;  ldW = 2048; nmax = 2048; noff = 0; }
    else if (z == 1) { src = Wk; dst = Wt;  ldW = 512;  nmax = 512;  noff = 2048; }
    else if (z == 2) { src = Wv; dst = Wt;  ldW = 512;  nmax = 512;  noff = 2560; }
    else             { src = Wo; dst = Wot; ldW = 2048; nmax = 2048; noff = 0; }
    int n0 = blockIdx.y * 64;
    if (n0 >= nmax) return;
    int k0 = blockIdx.x * 64;
    int tx = threadIdx.x & 15, ty = threadIdx.x >> 4;
#pragma unroll
    for (int i = 0; i < 4; ++i) {
        int r = ty + i * 16;
        float4 v4 = *(const float4*)&src[(size_t)(k0 + r) * ldW + n0 + tx * 4];
        tile[r][tx * 4 + 0] = v4.x;
        tile[r][tx * 4 + 1] = v4.y;
        tile[r][tx * 4 + 2] = v4.z;
        tile[r][tx * 4 + 3] = v4.w;
    }
    __syncthreads();
#pragma unroll
    for (int i = 0; i < 4; ++i) {
        int r = ty + i * 16;     // n-local
        int c = tx * 4;          // k-local
        ushort4 o;
        o.x = f2bf(tile[c + 0][r]);
        o.y = f2bf(tile[c + 1][r]);
        o.z = f2bf(tile[c + 2][r]);
        o.w = f2bf(tile[c + 3][r]);
        *(ushort4*)&dst[(size_t)(noff + n0 + r) * 2048 + k0 + c] = o;
    }
}

// ---------------------------------------------------------------------------
// MFMA GEMM core 128x128x64, 4 waves, 16x16x32 bf16, global_load_lds staging,
// XOR-swizzled k-chunks.  mrow/nrow give each wave's 4 m/n tile bases.
// ---------------------------------------------------------------------------
__device__ __forceinline__ void gemm_core_128x128x64(
    const unsigned short* __restrict__ A, const unsigned short* __restrict__ B,
    short* As, short* Bs, int m0, int n0,
    const int* mrow, const int* nrow, f32x4 (&acc)[4][4])
{
    const int tid = threadIdx.x;
    const int lane = tid & 63;
    const int w = tid >> 6;
    const int lm = lane & 15;
    const int q8 = lane >> 4;
    const int lrow = lane >> 3;            // 0..7 within an instr's 8 rows
    const int lchunk = lane & 7;           // lane's LDS chunk slot

    for (int kt = 0; kt < CC; kt += 64) {
        __syncthreads();                   // prev iter frag reads complete
#pragma unroll
        for (int jj = 0; jj < 4; ++jj) {
            int rA = w * 32 + jj * 8 + lrow;
            int cA = ((lchunk ^ (rA & 7)) << 3);
            __builtin_amdgcn_global_load_lds(
                GLOBAL_AS(&A[(size_t)(m0 + rA) * CC + kt + cA]),
                LDS_AS(&As[(w * 32 + jj * 8) * 64]), 16, 0, 0);
            __builtin_amdgcn_global_load_lds(
                GLOBAL_AS(&B[(size_t)(n0 + rA) * CC + kt + cA]),
                LDS_AS(&Bs[(w * 32 + jj * 8) * 64]), 16, 0, 0);
        }
        __syncthreads();                   // vmcnt drained -> tiles visible
#pragma unroll
        for (int ksi = 0; ksi < 2; ++ksi) {
            bf16x8 af[4], bfr[4];
#pragma unroll
            for (int i = 0; i < 4; ++i) {
                int xo = (((ksi * 4 + q8) ^ (lm & 7)) << 3);
                af[i]  = *(const bf16x8*)&As[(mrow[i] + lm) * 64 + xo];
                bfr[i] = *(const bf16x8*)&Bs[(nrow[i] + lm) * 64 + xo];
            }
#pragma unroll
            for (int im = 0; im < 4; ++im)
#pragma unroll
                for (int in = 0; in < 4; ++in)
                    acc[im][in] = __builtin_amdgcn_mfma_f32_16x16x32_bf16(af[im], bfr[in], acc[im][in], 0, 0, 0);
        }
    }
}

// ---------------------------------------------------------------------------
// QKV GEMM with fused bias + RoPE + q-scale.  Each 128-col block is exactly
// one head (HD=128).  Wave n-tiles remapped to {w1*32+(in&1)*16+(in>>1)*64}
// so d and d^64 are in the SAME lane at in^2 -> in-register RoPE.
// ---------------------------------------------------------------------------
__global__ __launch_bounds__(256, 3) void qkv_gemm_mfma(
    const unsigned short* __restrict__ xb, const unsigned short* __restrict__ Wt,
    const float* __restrict__ bq, const float* __restrict__ bk, const float* __restrict__ bv,
    const float* __restrict__ cosb, const float* __restrict__ sinb,
    unsigned short* __restrict__ q, unsigned short* __restrict__ k, unsigned short* __restrict__ v)
{
    __shared__ __attribute__((aligned(16))) short As[128 * 64];
    __shared__ __attribute__((aligned(16))) short Bs[128 * 64];
    const int lane = threadIdx.x & 63;
    const int w = threadIdx.x >> 6;
    const int w1 = w >> 1;
    const int m0 = blockIdx.y * 128;
    const int n0 = blockIdx.x * 128;
    const int lm = lane & 15;
    const int q8 = lane >> 4;

    int mrow[4], nrow[4];
#pragma unroll
    for (int i = 0; i < 4; ++i) {
        mrow[i] = (w & 1) * 64 + i * 16;
        nrow[i] = w1 * 32 + (i & 1) * 16 + (i >> 1) * 64;   // d and d^64 at in^2
    }

    f32x4 acc[4][4];
#pragma unroll
    for (int im = 0; im < 4; ++im)
#pragma unroll
        for (int in = 0; in < 4; ++in) acc[im][in] = {0.f, 0.f, 0.f, 0.f};

    gemm_core_128x128x64(xb, Wt, As, Bs, m0, n0, mrow, nrow, acc);

    unsigned short* dst; const float* bias; int ldD, off, mode;
    if (n0 < 2048)      { dst = q; bias = bq; ldD = 2048; off = n0;        mode = 0; }
    else if (n0 < 2560) { dst = k; bias = bk; ldD = 512;  off = n0 - 2048; mode = 1; }
    else                { dst = v; bias = bv; ldD = 512;  off = n0 - 2560; mode = 2; }

    float bv_[4];
#pragma unroll
    for (int in = 0; in < 4; ++in) bv_[in] = bias[off + nrow[in] + lm];

#pragma unroll
    for (int im = 0; im < 4; ++im) {
        int rowbase = m0 + mrow[im] + q8 * 4;
        float t[4][4];                      // [in][r], biased pre-rope values
#pragma unroll
        for (int in = 0; in < 4; ++in)
#pragma unroll
            for (int r = 0; r < 4; ++r) t[in][r] = acc[im][in][r] + bv_[in];
        if (mode < 2) {                     // rope (q and k)
#pragma unroll
            for (int in = 0; in < 4; ++in) {
                int d = nrow[in] + lm;
                float sgn = (in < 2) ? -1.f : 1.f;   // d<64 <=> in<2
#pragma unroll
                for (int r = 0; r < 4; ++r) {
                    int row = rowbase + r;
                    float c = cosb[row * HD + d];
                    float s = sinb[row * HD + d];
                    float o = c * t[in][r] + sgn * s * t[in ^ 2][r];
                    if (mode == 0) o *= QSCALE;
                    dst[(size_t)row * ldD + off + d] = f2bf(o);
                }
            }
        } else {                            // v: bias only
#pragma unroll
            for (int in = 0; in < 4; ++in)
#pragma unroll
                for (int r = 0; r < 4; ++r)
                    dst[(size_t)(rowbase + r) * ldD + off + nrow[in] + lm] = f2bf(t[in][r]);
        }
    }
}

__global__ __launch_bounds__(256, 3) void out_gemm_mfma(
    const unsigned short* __restrict__ yb, const unsigned short* __restrict__ Wot,
    float* __restrict__ Cout)
{
    __shared__ __attribute__((aligned(16))) short As[128 * 64];
    __shared__ __attribute__((aligned(16))) short Bs[128 * 64];
    const int lane = threadIdx.x & 63;
    const int w = threadIdx.x >> 6;
    const int m0 = blockIdx.y * 128;
    const int n0 = blockIdx.x * 128;
    const int lm = lane & 15;
    const int q8 = lane >> 4;

    int mrow[4], nrow[4];
#pragma unroll
    for (int i = 0; i < 4; ++i) {
        mrow[i] = (w & 1) * 64 + i * 16;
        nrow[i] = (w >> 1) * 64 + i * 16;
    }

    f32x4 acc[4][4];
#pragma unroll
    for (int im = 0; im < 4; ++im)
#pragma unroll
        for (int in = 0; in < 4; ++in) acc[im][in] = {0.f, 0.f, 0.f, 0.f};

    gemm_core_128x128x64(yb, Wot, As, Bs, m0, n0, mrow, nrow, acc);

#pragma unroll
    for (int im = 0; im < 4; ++im)
#pragma unroll
        for (int in = 0; in < 4; ++in)
#pragma unroll
            for (int r = 0; r < 4; ++r) {
                int row = m0 + mrow[im] + q8 * 4 + r;
                Cout[(size_t)row * CC + n0 + nrow[in] + lm] = acc[im][in][r];
            }
}

// ---------------------------------------------------------------------------
// V transpose: v[b][t][g*128+d] bf16 -> vt[(b*4+g)*128+d][t] bf16
// ---------------------------------------------------------------------------
__global__ __launch_bounds__(256) void vtrans_kernel(
    const unsigned short* __restrict__ v, unsigned short* __restrict__ vt)
{
    __shared__ unsigned short tile[64][68];
    int bg = blockIdx.z;           // b*4+g
    int b = bg >> 2, g = bg & 3;
    int t0 = blockIdx.x * 64;
    int d0 = blockIdx.y * 64;
    int tx = threadIdx.x & 15, ty = threadIdx.x >> 4;
#pragma unroll
    for (int i = 0; i < 4; ++i) {
        int r = ty + i * 16;
        ushort4 v4 = *(const ushort4*)&v[(size_t)(b * TT + t0 + r) * (HKK * HD) + g * HD + d0 + tx * 4];
        tile[r][tx * 4 + 0] = v4.x;
        tile[r][tx * 4 + 1] = v4.y;
        tile[r][tx * 4 + 2] = v4.z;
        tile[r][tx * 4 + 3] = v4.w;
    }
    __syncthreads();
#pragma unroll
    for (int i = 0; i < 4; ++i) {
        int r = ty + i * 16;   // d-local
        int c = tx * 4;        // t-local
        ushort4 o;
        o.x = tile[c + 0][r];
        o.y = tile[c + 1][r];
        o.z = tile[c + 2][r];
        o.w = tile[c + 3][r];
        *(ushort4*)&vt[(size_t)(bg * HD + d0 + r) * TT + t0 + c] = o;
    }
}

// ---------------------------------------------------------------------------
// Work-item table (unchanged from r2): 24 items per (b,h), tiers of 8 sum 34
// iter-units per CU-triple.  qi 0..7 unsplit (hf=2); qi 8..15 split in two
// KV halves (hf=0/1).
// ---------------------------------------------------------------------------
static __device__ const signed char QI_T[24] = {
    15, 7, 14, 14, 13, 6, 12, 11,
    15, 13, 12, 10, 10, 9, 11, 5,
    0, 1, 2, 3, 8, 4, 8, 9
};
static __device__ const signed char HF_T[24] = {
    0, 2, 0, 1, 1, 2, 1, 1,
    1, 0, 0, 0, 1, 0, 0, 2,
    2, 2, 2, 2, 0, 2, 1, 1
};

// ---------------------------------------------------------------------------
// MFMA flash attention v4: 32x32x16 MFMAs, 256 threads (4 waves), BR=128
// (wave owns 32 q-rows), BC=64.
//   * S^T = K·Q^T per 32x32 tile: C col=lane&31 = qrow, regs = token ->
//     softmax reduction is per-lane over 32 regs + 1 shfl_xor(32).
//   * PV computed as O^T = V^T·P^T:  o_acc = mfma(vf, pa, o_acc).
//     *** r3 BUG (absmax 6.8): mfma(pa, vf) puts qrow in REGS and d in the
//     lane index, but alpha/invl/epilogue assume qrow = lane&31.  Swapping
//     the operands gives C[m=d (regs)][n=qrow (lane)] — vf is a valid
//     A-operand (V^T[d][tok], same Vs reads) and pa a valid B-operand
//     (P^T[tok][qrow], identical fragment since A-row/B-col lane maps
//     coincide).  Everything downstream is per-lane qrow as intended. ***
//   * P never touches LDS: f32->bf16 via v_cvt_pk_bf16_f32, then one
//     v_permlane32_swap_b32 per word pair (vdst.hi <-> vsrc.lo) builds the
//     PV B-fragment in-register:
//       frag[ks] elem e (lane l31,hi): tok=16ks+8hi+e, value held at
//       reg=(e&3)+4*(2(ks&1)+hi) of the lane with hi_src=(e>>2)&1.
//       With a=W[2(ks&1)+0][j], b=W[2(ks&1)+1][j]: swap(a,b) -> a=words
//       {e<4}, b=words {e>=4} for BOTH halves.
//   * VGPR ~230: launch_bounds (256,2); LDS 35840 B.  2 blocks/CU resident
//     (reg-limited); tier table still balances (pair sums 24..32 + tier-3
//     backfill = 34 everywhere).
// Split chunks (hf<2) write normalized partials to po/sb; combine_kernel
// merges.  Unsplit chunks keep the LDS-staged coalesced bf16 y epilogue.
// ---------------------------------------------------------------------------
__global__ __launch_bounds__(256, 2) void flash_mfma(
    const unsigned short* __restrict__ q, const unsigned short* __restrict__ k,
    const unsigned short* __restrict__ vt, unsigned short* __restrict__ y,
    float* __restrict__ po, float* __restrict__ sb)
{
    // Ks 64x136 (8704) | Vs 128x72 (9216)  = 17920 shorts = 35840 B
    __shared__ __attribute__((aligned(16))) short SM[17920];
    short* Ks = SM;
    short* Vs = SM + 8704;

    const int tid = threadIdx.x;
    const int lane = tid & 63;
    const int w = tid >> 6;               // 0..3
    const int l31 = lane & 31;
    const int hi = lane >> 5;
    const int bh = blockIdx.x;            // 0..31
    const int b = bh >> 4, h = bh & 15, g = h >> 2;
    const int yb_ = blockIdx.y;           // 0..23
    const int qi = QI_T[yb_];
    const int hf = HF_T[yb_];             // 0/1 = split half, 2 = unsplit
    const int q0 = qi * 128;
    const int jdiag = 2 * qi + (w >> 1);  // this wave's diagonal tile
    int j0, jend;
    if (hf == 2)      { j0 = 0;      jend = 2 * qi + 2; }
    else if (hf == 0) { j0 = 0;      jend = qi + 1; }
    else              { j0 = qi + 1; jend = 2 * qi + 2; }

    // Q fragments: B-operand of S^T = K·Q^T. col=qrow=l31, k=ks*16+hi*8+e
    bf16x8 qf[8];
#pragma unroll
    for (int ks = 0; ks < 8; ++ks)
        qf[ks] = *(const bf16x8*)&q[(size_t)(b * TT + q0 + w * 32 + l31) * CC
                                    + h * HD + ks * 16 + hi * 8];

    f32x16 o_acc[4];
#pragma unroll
    for (int t = 0; t < 4; ++t)
#pragma unroll
        for (int e = 0; e < 16; ++e) o_acc[t][e] = 0.f;
    float m_i = -1e30f;                   // per-lane running max (exp2 domain)
    float l_i = 0.f;                      // per-lane partial row sum (hi half)

    // staging: 1024 16B-chunks each for K and V over 256 threads (4 each)
    int ktok[4], ke8[4], vd[4], vt8[4];
#pragma unroll
    for (int i = 0; i < 4; ++i) {
        int f = tid + i * 256;
        ktok[i] = f >> 4; ke8[i] = (f & 15) * 8;
        vd[i]   = f >> 3; vt8[i] = (f & 7) * 8;
    }
    const unsigned short* kbase = k + (size_t)(b * TT) * (HKK * HD) + g * HD;
    const unsigned short* vbase = vt + (size_t)((b * 4 + g) * HD) * TT;

    uint4 kreg[4], vreg[4];
#pragma unroll
    for (int i = 0; i < 4; ++i) {
        kreg[i] = *(const uint4*)&kbase[(size_t)(j0 * 64 + ktok[i]) * (HKK * HD) + ke8[i]];
        vreg[i] = *(const uint4*)&vbase[(size_t)vd[i] * TT + j0 * 64 + vt8[i]];
    }

    for (int j = j0; j < jend; ++j) {
        __syncthreads();                 // prev iter's K/V LDS reads complete
#pragma unroll
        for (int i = 0; i < 4; ++i) {
            *(uint4*)&Ks[ktok[i] * 136 + ke8[i]] = kreg[i];
            *(uint4*)&Vs[vd[i] * 72 + vt8[i]]    = vreg[i];
        }
        __syncthreads();                 // tiles visible
        if (j + 1 < jend) {              // prefetch next tile (uniform branch)
#pragma unroll
            for (int i = 0; i < 4; ++i) {
                kreg[i] = *(const uint4*)&kbase[(size_t)((j + 1) * 64 + ktok[i]) * (HKK * HD) + ke8[i]];
                vreg[i] = *(const uint4*)&vbase[(size_t)vd[i] * TT + (j + 1) * 64 + vt8[i]];
            }
        }

        if (j <= jdiag) {
            // S^T = K·Q^T, two 32x32 tok-tiles.  A=K: row=tok=ct*32+l31,
            // k=ks*16+hi*8+e.
            f32x16 sacc[2];
#pragma unroll
            for (int ct = 0; ct < 2; ++ct) {
#pragma unroll
                for (int e = 0; e < 16; ++e) sacc[ct][e] = 0.f;
#pragma unroll
                for (int ks = 0; ks < 8; ++ks) {
                    bf16x8 kf = *(const bf16x8*)&Ks[(ct * 32 + l31) * 136 + ks * 16 + hi * 8];
                    sacc[ct] = __builtin_amdgcn_mfma_f32_32x32x16_bf16(kf, qf[ks], sacc[ct], 0, 0, 0);
                }
            }
            if (j == jdiag) {            // causal mask (diagonal tile only)
                int lim = l31 + 32 * (w & 1);   // tok_local > lim -> masked
#pragma unroll
                for (int ct = 0; ct < 2; ++ct)
#pragma unroll
                    for (int reg = 0; reg < 16; ++reg) {
                        int tok = ct * 32 + (reg & 3) + 8 * (reg >> 2) + 4 * hi;
                        if (tok > lim) sacc[ct][reg] = -1e30f;
                    }
            }
            // per-lane row max over 32 values + 1 cross-half shfl
            float tmax = sacc[0][0];
#pragma unroll
            for (int e = 1; e < 16; ++e) tmax = fmaxf(tmax, sacc[0][e]);
#pragma unroll
            for (int e = 0; e < 16; ++e) tmax = fmaxf(tmax, sacc[1][e]);
            tmax = fmaxf(tmax, __shfl_xor(tmax, 32));
            float m_new = fmaxf(m_i, tmax);
            float alpha = exp2f(m_i - m_new);
            m_i = m_new;

            float p[2][16];
            float ps = 0.f;
#pragma unroll
            for (int ct = 0; ct < 2; ++ct)
#pragma unroll
                for (int reg = 0; reg < 16; ++reg) {
                    p[ct][reg] = exp2f(sacc[ct][reg] - m_new);
                    ps += p[ct][reg];
                }
            l_i = l_i * alpha + ps;

            // rescale O (per-lane scalar alpha; o_acc qrow = l31 after swap)
#pragma unroll
            for (int t = 0; t < 4; ++t)
#pragma unroll
                for (int e = 0; e < 16; ++e) o_acc[t][e] *= alpha;

            // pack P to bf16 words: W[ct][b][j] = pk(p[4b+2j], p[4b+2j+1])
            int W[2][4][2];
#pragma unroll
            for (int ct = 0; ct < 2; ++ct)
#pragma unroll
                for (int bb = 0; bb < 4; ++bb)
#pragma unroll
                    for (int jj = 0; jj < 2; ++jj)
                        asm("v_cvt_pk_bf16_f32 %0, %1, %2"
                            : "=v"(W[ct][bb][jj])
                            : "v"(p[ct][4 * bb + 2 * jj]), "v"(p[ct][4 * bb + 2 * jj + 1]));

            // O^T += V^T·P^T : A=V from LDS, B=P in-register via permlane
#pragma unroll
            for (int ks = 0; ks < 4; ++ks) {
                int a0 = W[ks >> 1][2 * (ks & 1)][0];
                int a1 = W[ks >> 1][2 * (ks & 1)][1];
                int b0 = W[ks >> 1][2 * (ks & 1) + 1][0];
                int b1 = W[ks >> 1][2 * (ks & 1) + 1][1];
                asm("v_permlane32_swap_b32 %0, %1" : "+v"(a0), "+v"(b0));
                asm("v_permlane32_swap_b32 %0, %1" : "+v"(a1), "+v"(b1));
                i32x4 wv; wv[0] = a0; wv[1] = a1; wv[2] = b0; wv[3] = b1;
                bf16x8 pa = __builtin_bit_cast(bf16x8, wv);
#pragma unroll
                for (int t = 0; t < 4; ++t) {
                    bf16x8 vf = *(const bf16x8*)&Vs[(t * 32 + l31) * 72 + ks * 16 + hi * 8];
                    o_acc[t] = __builtin_amdgcn_mfma_f32_32x32x16_bf16(vf, pa, o_acc[t], 0, 0, 0);
                }
            }
        }
    }

    // finalize l: add the other 32-lane half's partial
    float lf = l_i + __shfl_xor(l_i, 32);
    float invl = 1.f / lf;

    if (hf == 2) {
        // Epilogue: stage O in LDS (128 rows x stride 136 over Ks/Vs space),
        // read back b128, store coalesced dwordx4.
        // o_acc[t][reg] = O[qrow=l31][d = t*32 + (reg&3) + 8*(reg>>2) + 4*hi]
        __syncthreads();                   // all waves done with Ks/Vs
        short* Es = SM;                    // 128*136 = 17408 <= 17920 shorts
#pragma unroll
        for (int t = 0; t < 4; ++t)
#pragma unroll
            for (int rg = 0; rg < 4; ++rg) {
                ushort4 o;
                o.x = f2bf(o_acc[t][rg * 4 + 0] * invl);
                o.y = f2bf(o_acc[t][rg * 4 + 1] * invl);
                o.z = f2bf(o_acc[t][rg * 4 + 2] * invl);
                o.w = f2bf(o_acc[t][rg * 4 + 3] * invl);
                // d = t*32 + 8*rg + 4*hi + {0..3}
                *(ushort4*)&Es[(w * 32 + l31) * 136 + t * 32 + 8 * rg + 4 * hi] = o;
            }
        __syncthreads();
#pragma unroll
        for (int i = 0; i < 8; ++i) {
            int f = tid + i * 256;             // 0..2047
            int row = f >> 4, ch = f & 15;
            uint4 tv = *(const uint4*)&Es[row * 136 + ch * 8];
            *(uint4*)&y[(size_t)(b * TT + q0 + row) * CC + h * HD + ch * 8] = tv;
        }
    } else {
        // Split-chunk epilogue: normalized Ô (f32) + per-row s = l·2^m.
        const int pi = ((bh << 3) + (qi - 8)) * 2 + hf;
        if (hi == 0) sb[pi * 128 + w * 32 + l31] = lf * exp2f(m_i);
        float* pb = po + (size_t)pi * 16384;
#pragma unroll
        for (int t = 0; t < 4; ++t)
#pragma unroll
            for (int rg = 0; rg < 4; ++rg) {
                float4 o;
                o.x = o_acc[t][rg * 4 + 0] * invl;
                o.y = o_acc[t][rg * 4 + 1] * invl;
                o.z = o_acc[t][rg * 4 + 2] * invl;
                o.w = o_acc[t][rg * 4 + 3] * invl;
                *(float4*)&pb[(w * 32 + l31) * 128 + t * 32 + 8 * rg + 4 * hi] = o;
            }
    }
}

// ---------------------------------------------------------------------------
// Merge the two KV-half partials of split tiles (qi 8..15):
//   O = (s0·Ô0 + s1·Ô1)/(s0+s1),  then bf16 -> y.
// ---------------------------------------------------------------------------
__global__ __launch_bounds__(256) void combine_kernel(
    const float* __restrict__ po, const float* __restrict__ sb,
    unsigned short* __restrict__ y)
{
    const int bh = blockIdx.x;             // 0..31
    const int b = bh >> 4, h = bh & 15;
    const int qi = 8 + blockIdx.y;         // 8..15
    const int p0 = ((bh << 3) + (qi - 8)) * 2;
    const int t = threadIdx.x;
    const int row = t >> 1, d0 = (t & 1) * 64;
    float s0 = sb[p0 * 128 + row];
    float s1 = sb[(p0 + 1) * 128 + row];
    float w0 = s0 / (s0 + s1);
    float w1 = 1.f - w0;
    const float* a = &po[(size_t)p0 * 16384 + row * 128 + d0];
    const float* c = &po[(size_t)(p0 + 1) * 16384 + row * 128 + d0];
    unsigned short* yr = &y[(size_t)(b * TT + qi * 128 + row) * CC + h * HD + d0];
#pragma unroll
    for (int i = 0; i < 64; i += 4) {
        float4 xa = *(const float4*)&a[i];
        float4 xc = *(const float4*)&c[i];
        ushort4 o;
        o.x = f2bf(w0 * xa.x + w1 * xc.x);
        o.y = f2bf(w0 * xa.y + w1 * xc.y);
        o.z = f2bf(w0 * xa.z + w1 * xc.z);
        o.w = f2bf(w0 * xa.w + w1 * xc.w);
        *(ushort4*)&yr[i] = o;
    }
}

// ---------------------------------------------------------------------------
extern "C" void kernel_launch(void* const* d_in, const int* in_sizes, int n_in,
                              void* d_out, int out_size, void* d_ws, size_t ws_size,
                              hipStream_t stream) {
    const float* x    = (const float*)d_in[0];
    const float* cosb = (const float*)d_in[1];
    const float* sinb = (const float*)d_in[2];
    const float* Wq   = (const float*)d_in[3];
    const float* bq   = (const float*)d_in[4];
    const float* Wk   = (const float*)d_in[5];
    const float* bk   = (const float*)d_in[6];
    const float* Wv   = (const float*)d_in[7];
    const float* bv   = (const float*)d_in[8];
    const float* Wo   = (const float*)d_in[9];
    float* out = (float*)d_out;

    // workspace (all bf16 as ushort):
    // xb[4096*2048] Wt[3072*2048] Wot[2048*2048] qb[4096*2048]
    // kb[4096*512] vb[4096*512] vtb[1024*2048] yb[4096*2048]  = 83.9 MB
    unsigned short* xb  = (unsigned short*)d_ws;
    unsigned short* Wt  = xb  + (size_t)MM * CC;
    unsigned short* Wot = Wt  + (size_t)3072 * 2048;
    unsigned short* qb  = Wot + (size_t)2048 * 2048;
    unsigned short* kb  = qb  + (size_t)MM * CC;
    unsigned short* vb  = kb  + (size_t)MM * (HKK * HD);
    unsigned short* vtb = vb  + (size_t)MM * (HKK * HD);
    unsigned short* ybf = vtb + (size_t)BB * HKK * HD * TT;

    // Scratch aliases for the split-KV flash path (no new workspace):
    //  - po: 512 partial tiles x 128x128 f32 = 33.55 MB == d_out size exactly
    //        (d_out is dead until out_gemm overwrites every element).
    //  - sb: 512x128 f32 row-scalars s = l*2^m, over dead xb (dead after qkv).
    float* po = (float*)d_out;
    float* sbuf = (float*)xb;

    cast_x_kernel<<<dim3((MM * CC) / 2048), 256, 0, stream>>>(x, xb);
    wtrans_kernel<<<dim3(32, 32, 4), 256, 0, stream>>>(Wq, Wk, Wv, Wo, Wt, Wot);
    qkv_gemm_mfma<<<dim3(3072 / 128, MM / 128), 256, 0, stream>>>(
        xb, Wt, bq, bk, bv, cosb, sinb, qb, kb, vb);
    vtrans_kernel<<<dim3(TT / 64, HD / 64, BB * HKK), 256, 0, stream>>>(vb, vtb);
    flash_mfma<<<dim3(BB * HH, 24), 256, 0, stream>>>(qb, kb, vtb, ybf, po, sbuf);
    combine_kernel<<<dim3(BB * HH, 8), 256, 0, stream>>>(po, sbuf, ybf);
    out_gemm_mfma<<<dim3(CC / 128, MM / 128), 256, 0, stream>>>(ybf, Wot, out);
}

// Round 5
// 318.044 us; speedup vs baseline: 1.2444x; 1.2444x over previous
//
#include <hip/hip_runtime.h>
#include <math.h>

// Problem constants
#define BB 2
#define TT 2048
#define CC 2048
#define HH 16
#define HKK 4
#define HD 128
#define MM (BB*TT)          // 4096 rows

typedef short bf16x8 __attribute__((ext_vector_type(8)));
typedef float f32x4 __attribute__((ext_vector_type(4)));
typedef float f32x16 __attribute__((ext_vector_type(16)));
typedef int   i32x4 __attribute__((ext_vector_type(4)));

#define GLOBAL_AS(p) ((const __attribute__((address_space(1))) void*)(p))
#define LDS_AS(p)    ((__attribute__((address_space(3))) void*)(p))

__device__ __forceinline__ unsigned short f2bf(float f) {
    unsigned u = __float_as_uint(f);
    u += 0x7fff + ((u >> 16) & 1);          // round-to-nearest-even
    return (unsigned short)(u >> 16);
}
__device__ __forceinline__ float bf2f(unsigned short h) {
    return __uint_as_float(((unsigned)h) << 16);
}

// softmax scale 1/sqrt(128) * log2(e), folded into q at projection time
#define QSCALE (0.08838834764831845f * 1.44269504088896340736f)

// ---------------------------------------------------------------------------
// cast x (f32 -> bf16), 8 elements/thread
// ---------------------------------------------------------------------------
__global__ __launch_bounds__(256) void cast_x_kernel(
    const float* __restrict__ x, unsigned short* __restrict__ xb)
{
    size_t i = ((size_t)blockIdx.x * 256 + threadIdx.x) * 8;
    float4 a = *(const float4*)&x[i];
    float4 b = *(const float4*)&x[i + 4];
    uint4 r;
    r.x = f2bf(a.x) | ((unsigned)f2bf(a.y) << 16);
    r.y = f2bf(a.z) | ((unsigned)f2bf(a.w) << 16);
    r.z = f2bf(b.x) | ((unsigned)f2bf(b.y) << 16);
    r.w = f2bf(b.z) | ((unsigned)f2bf(b.w) << 16);
    *(uint4*)&xb[i] = r;
}

// ---------------------------------------------------------------------------
// Weight transpose+cast: W[K][N] f32 -> Wt[N][K] bf16.
// ---------------------------------------------------------------------------
__global__ __launch_bounds__(256) void wtrans_kernel(
    const float* __restrict__ Wq, const float* __restrict__ Wk,
    const float* __restrict__ Wv, const float* __restrict__ Wo,
    unsigned short* __restrict__ Wt, unsigned short* __restrict__ Wot)
{
    __shared__ float tile[64][65];
    int z = blockIdx.z;
    const float* src; unsigned short* dst; int ldW, nmax, noff;
    if (z == 0)      { src = Wq; dst = Wt;  ldW = 2048; nmax = 2048; noff = 0; }
    else if (z == 1) { src = Wk; dst = Wt;  ldW = 512;  nmax = 512;  noff = 2048; }
    else if (z == 2) { src = Wv; dst = Wt;  ldW = 512;  nmax = 512;  noff = 2560; }
    else             { src = Wo; dst = Wot; ldW = 2048; nmax = 2048; noff = 0; }
    int n0 = blockIdx.y * 64;
    if (n0 >= nmax) return;
    int k0 = blockIdx.x * 64;
    int tx = threadIdx.x & 15, ty = threadIdx.x >> 4;
#pragma unroll
    for (int i = 0; i < 4; ++i) {
        int r = ty + i * 16;
        float4 v4 = *(const float4*)&src[(size_t)(k0 + r) * ldW + n0 + tx * 4];
        tile[r][tx * 4 + 0] = v4.x;
        tile[r][tx * 4 + 1] = v4.y;
        tile[r][tx * 4 + 2] = v4.z;
        tile[r][tx * 4 + 3] = v4.w;
    }
    __syncthreads();
#pragma unroll
    for (int i = 0; i < 4; ++i) {
        int r = ty + i * 16;     // n-local
        int c = tx * 4;          // k-local
        ushort4 o;
        o.x = f2bf(tile[c + 0][r]);
        o.y = f2bf(tile[c + 1][r]);
        o.z = f2bf(tile[c + 2][r]);
        o.w = f2bf(tile[c + 3][r]);
        *(ushort4*)&dst[(size_t)(noff + n0 + r) * 2048 + k0 + c] = o;
    }
}

// ---------------------------------------------------------------------------
// MFMA GEMM core 128x128x64, 4 waves, 16x16x32 bf16, global_load_lds staging,
// XOR-swizzled k-chunks.  mrow/nrow give each wave's 4 m/n tile bases.
// ---------------------------------------------------------------------------
__device__ __forceinline__ void gemm_core_128x128x64(
    const unsigned short* __restrict__ A, const unsigned short* __restrict__ B,
    short* As, short* Bs, int m0, int n0,
    const int* mrow, const int* nrow, f32x4 (&acc)[4][4])
{
    const int tid = threadIdx.x;
    const int lane = tid & 63;
    const int w = tid >> 6;
    const int lm = lane & 15;
    const int q8 = lane >> 4;
    const int lrow = lane >> 3;            // 0..7 within an instr's 8 rows
    const int lchunk = lane & 7;           // lane's LDS chunk slot

    for (int kt = 0; kt < CC; kt += 64) {
        __syncthreads();                   // prev iter frag reads complete
#pragma unroll
        for (int jj = 0; jj < 4; ++jj) {
            int rA = w * 32 + jj * 8 + lrow;
            int cA = ((lchunk ^ (rA & 7)) << 3);
            __builtin_amdgcn_global_load_lds(
                GLOBAL_AS(&A[(size_t)(m0 + rA) * CC + kt + cA]),
                LDS_AS(&As[(w * 32 + jj * 8) * 64]), 16, 0, 0);
            __builtin_amdgcn_global_load_lds(
                GLOBAL_AS(&B[(size_t)(n0 + rA) * CC + kt + cA]),
                LDS_AS(&Bs[(w * 32 + jj * 8) * 64]), 16, 0, 0);
        }
        __syncthreads();                   // vmcnt drained -> tiles visible
#pragma unroll
        for (int ksi = 0; ksi < 2; ++ksi) {
            bf16x8 af[4], bfr[4];
#pragma unroll
            for (int i = 0; i < 4; ++i) {
                int xo = (((ksi * 4 + q8) ^ (lm & 7)) << 3);
                af[i]  = *(const bf16x8*)&As[(mrow[i] + lm) * 64 + xo];
                bfr[i] = *(const bf16x8*)&Bs[(nrow[i] + lm) * 64 + xo];
            }
#pragma unroll
            for (int im = 0; im < 4; ++im)
#pragma unroll
                for (int in = 0; in < 4; ++in)
                    acc[im][in] = __builtin_amdgcn_mfma_f32_16x16x32_bf16(af[im], bfr[in], acc[im][in], 0, 0, 0);
        }
    }
}

// ---------------------------------------------------------------------------
// QKV GEMM with fused bias + RoPE + q-scale.  Each 128-col block is exactly
// one head (HD=128).  Wave n-tiles remapped to {w1*32+(in&1)*16+(in>>1)*64}
// so d and d^64 are in the SAME lane at in^2 -> in-register RoPE.
// ---------------------------------------------------------------------------
__global__ __launch_bounds__(256, 3) void qkv_gemm_mfma(
    const unsigned short* __restrict__ xb, const unsigned short* __restrict__ Wt,
    const float* __restrict__ bq, const float* __restrict__ bk, const float* __restrict__ bv,
    const float* __restrict__ cosb, const float* __restrict__ sinb,
    unsigned short* __restrict__ q, unsigned short* __restrict__ k, unsigned short* __restrict__ v)
{
    __shared__ __attribute__((aligned(16))) short As[128 * 64];
    __shared__ __attribute__((aligned(16))) short Bs[128 * 64];
    const int lane = threadIdx.x & 63;
    const int w = threadIdx.x >> 6;
    const int w1 = w >> 1;
    const int m0 = blockIdx.y * 128;
    const int n0 = blockIdx.x * 128;
    const int lm = lane & 15;
    const int q8 = lane >> 4;

    int mrow[4], nrow[4];
#pragma unroll
    for (int i = 0; i < 4; ++i) {
        mrow[i] = (w & 1) * 64 + i * 16;
        nrow[i] = w1 * 32 + (i & 1) * 16 + (i >> 1) * 64;   // d and d^64 at in^2
    }

    f32x4 acc[4][4];
#pragma unroll
    for (int im = 0; im < 4; ++im)
#pragma unroll
        for (int in = 0; in < 4; ++in) acc[im][in] = {0.f, 0.f, 0.f, 0.f};

    gemm_core_128x128x64(xb, Wt, As, Bs, m0, n0, mrow, nrow, acc);

    unsigned short* dst; const float* bias; int ldD, off, mode;
    if (n0 < 2048)      { dst = q; bias = bq; ldD = 2048; off = n0;        mode = 0; }
    else if (n0 < 2560) { dst = k; bias = bk; ldD = 512;  off = n0 - 2048; mode = 1; }
    else                { dst = v; bias = bv; ldD = 512;  off = n0 - 2560; mode = 2; }

    float bv_[4];
#pragma unroll
    for (int in = 0; in < 4; ++in) bv_[in] = bias[off + nrow[in] + lm];

#pragma unroll
    for (int im = 0; im < 4; ++im) {
        int rowbase = m0 + mrow[im] + q8 * 4;
        float t[4][4];                      // [in][r], biased pre-rope values
#pragma unroll
        for (int in = 0; in < 4; ++in)
#pragma unroll
            for (int r = 0; r < 4; ++r) t[in][r] = acc[im][in][r] + bv_[in];
        if (mode < 2) {                     // rope (q and k)
#pragma unroll
            for (int in = 0; in < 4; ++in) {
                int d = nrow[in] + lm;
                float sgn = (in < 2) ? -1.f : 1.f;   // d<64 <=> in<2
#pragma unroll
                for (int r = 0; r < 4; ++r) {
                    int row = rowbase + r;
                    float c = cosb[row * HD + d];
                    float s = sinb[row * HD + d];
                    float o = c * t[in][r] + sgn * s * t[in ^ 2][r];
                    if (mode == 0) o *= QSCALE;
                    dst[(size_t)row * ldD + off + d] = f2bf(o);
                }
            }
        } else {                            // v: bias only
#pragma unroll
            for (int in = 0; in < 4; ++in)
#pragma unroll
                for (int r = 0; r < 4; ++r)
                    dst[(size_t)(rowbase + r) * ldD + off + nrow[in] + lm] = f2bf(t[in][r]);
        }
    }
}

__global__ __launch_bounds__(256, 3) void out_gemm_mfma(
    const unsigned short* __restrict__ yb, const unsigned short* __restrict__ Wot,
    float* __restrict__ Cout)
{
    __shared__ __attribute__((aligned(16))) short As[128 * 64];
    __shared__ __attribute__((aligned(16))) short Bs[128 * 64];
    const int lane = threadIdx.x & 63;
    const int w = threadIdx.x >> 6;
    const int m0 = blockIdx.y * 128;
    const int n0 = blockIdx.x * 128;
    const int lm = lane & 15;
    const int q8 = lane >> 4;

    int mrow[4], nrow[4];
#pragma unroll
    for (int i = 0; i < 4; ++i) {
        mrow[i] = (w & 1) * 64 + i * 16;
        nrow[i] = (w >> 1) * 64 + i * 16;
    }

    f32x4 acc[4][4];
#pragma unroll
    for (int im = 0; im < 4; ++im)
#pragma unroll
        for (int in = 0; in < 4; ++in) acc[im][in] = {0.f, 0.f, 0.f, 0.f};

    gemm_core_128x128x64(yb, Wot, As, Bs, m0, n0, mrow, nrow, acc);

#pragma unroll
    for (int im = 0; im < 4; ++im)
#pragma unroll
        for (int in = 0; in < 4; ++in)
#pragma unroll
            for (int r = 0; r < 4; ++r) {
                int row = m0 + mrow[im] + q8 * 4 + r;
                Cout[(size_t)row * CC + n0 + nrow[in] + lm] = acc[im][in][r];
            }
}

// ---------------------------------------------------------------------------
// V transpose: v[b][t][g*128+d] bf16 -> vt[(b*4+g)*128+d][t] bf16
// ---------------------------------------------------------------------------
__global__ __launch_bounds__(256) void vtrans_kernel(
    const unsigned short* __restrict__ v, unsigned short* __restrict__ vt)
{
    __shared__ unsigned short tile[64][68];
    int bg = blockIdx.z;           // b*4+g
    int b = bg >> 2, g = bg & 3;
    int t0 = blockIdx.x * 64;
    int d0 = blockIdx.y * 64;
    int tx = threadIdx.x & 15, ty = threadIdx.x >> 4;
#pragma unroll
    for (int i = 0; i < 4; ++i) {
        int r = ty + i * 16;
        ushort4 v4 = *(const ushort4*)&v[(size_t)(b * TT + t0 + r) * (HKK * HD) + g * HD + d0 + tx * 4];
        tile[r][tx * 4 + 0] = v4.x;
        tile[r][tx * 4 + 1] = v4.y;
        tile[r][tx * 4 + 2] = v4.z;
        tile[r][tx * 4 + 3] = v4.w;
    }
    __syncthreads();
#pragma unroll
    for (int i = 0; i < 4; ++i) {
        int r = ty + i * 16;   // d-local
        int c = tx * 4;        // t-local
        ushort4 o;
        o.x = tile[c + 0][r];
        o.y = tile[c + 1][r];
        o.z = tile[c + 2][r];
        o.w = tile[c + 3][r];
        *(ushort4*)&vt[(size_t)(bg * HD + d0 + r) * TT + t0 + c] = o;
    }
}

// ---------------------------------------------------------------------------
// Work-item table (unchanged from r2): 24 items per (b,h).  qi 0..7 unsplit
// (hf=2); qi 8..15 split in two KV halves (hf=0/1).
// ---------------------------------------------------------------------------
static __device__ const signed char QI_T[24] = {
    15, 7, 14, 14, 13, 6, 12, 11,
    15, 13, 12, 10, 10, 9, 11, 5,
    0, 1, 2, 3, 8, 4, 8, 9
};
static __device__ const signed char HF_T[24] = {
    0, 2, 0, 1, 1, 2, 1, 1,
    1, 0, 0, 0, 1, 0, 0, 2,
    2, 2, 2, 2, 0, 2, 1, 1
};

// ---------------------------------------------------------------------------
// MFMA flash attention v5: 32x32x16 MFMAs, 256 threads (4 waves), BR=128,
// BC=64, double-buffered global_load_lds staging.
// r4 findings: 150us flat, Occupancy 16.8% (~1.3 blk/CU), WRITE 265MB vs
// 42MB payload = scratch spill (launch_bounds cap 256 regs, need ~290),
// plus 31-deep serial fmax/sum chains (~250 latency cyc/iter).
// Changes:
//   * p[2][16] eliminated: exp2 in place into sacc (-32 regs).
//   * kreg/vreg prefetch eliminated (-32 regs): K/V staged direct to LDS via
//     global_load_lds(16B) into 2x double-buffered LINEAR tiles
//     (Ks 64x128, Vs 128x64).  Swizzle is applied on the GLOBAL SOURCE
//     address (chunk ^= row&7, rule #21: source perm == read perm); LDS
//     dest stays linear (wave-uniform base + lane*16).  One barrier/iter;
//     stage of tile j+1 is issued before compute of tile j, loads stay in
//     flight across the compute (the barrier's implicit vmcnt(0) is the
//     completion wait).  Kills LDS-write VALU + the prefetch registers.
//   * max/sum restructured as trees (depth ~5 vs 31 serial).
//   * Regs now ~175 < 256 cap -> no spill possible; LDS 65536 B -> 2 blk/CU
//     (8 waves) co-resident for cross-block latency hiding.
// PV is O^T = V^T·P^T (r4 orientation, verified); P built in-register via
// v_cvt_pk_bf16_f32 + v_permlane32_swap_b32.  Split chunks write normalized
// partials to po/sb; combine_kernel merges.
// ---------------------------------------------------------------------------
__global__ __launch_bounds__(256, 2) void flash_mfma(
    const unsigned short* __restrict__ q, const unsigned short* __restrict__ k,
    const unsigned short* __restrict__ vt, unsigned short* __restrict__ y,
    float* __restrict__ po, float* __restrict__ sb)
{
    // buf c at SM + c*16384:  Ks 64x128 (8192 shorts) | Vs 128x64 (8192)
    // total 32768 shorts = 65536 B.  Epilogue Es (128x136=17408) reuses SM.
    __shared__ __attribute__((aligned(16))) short SM[32768];

    const int tid = threadIdx.x;
    const int lane = tid & 63;
    const int w = tid >> 6;               // 0..3
    const int l31 = lane & 31;
    const int hi = lane >> 5;
    const int swz = (l31 & 7) << 3;       // read-side XOR (shorts)
    const int bh = blockIdx.x;            // 0..31
    const int b = bh >> 4, h = bh & 15, g = h >> 2;
    const int yb_ = blockIdx.y;           // 0..23
    const int qi = QI_T[yb_];
    const int hf = HF_T[yb_];             // 0/1 = split half, 2 = unsplit
    const int q0 = qi * 128;
    const int jdiag = 2 * qi + (w >> 1);  // this wave's diagonal tile
    int j0, jend;
    if (hf == 2)      { j0 = 0;      jend = 2 * qi + 2; }
    else if (hf == 0) { j0 = 0;      jend = qi + 1; }
    else              { j0 = qi + 1; jend = 2 * qi + 2; }

    // Q fragments: B-operand of S^T = K·Q^T. col=qrow=l31, k=ks*16+hi*8+e
    bf16x8 qf[8];
#pragma unroll
    for (int ks = 0; ks < 8; ++ks)
        qf[ks] = *(const bf16x8*)&q[(size_t)(b * TT + q0 + w * 32 + l31) * CC
                                    + h * HD + ks * 16 + hi * 8];

    f32x16 o_acc[4];
#pragma unroll
    for (int t = 0; t < 4; ++t)
#pragma unroll
        for (int e = 0; e < 16; ++e) o_acc[t][e] = 0.f;
    float m_i = -1e30f;                   // per-lane running max (exp2 domain)
    float l_i = 0.f;                      // per-lane partial row sum

    // Staging geometry: per buffer 1024 K-chunks + 1024 V-chunks (16B each),
    // 4 issues/thread each.  Chunk c = (i*4+w)*64 + lane; K: tok=c>>4,
    // cc=c&15; V: d=c>>3, cc=c&7.  j-independent source offsets (shorts):
    const unsigned short* kbase = k + (size_t)(b * TT) * (HKK * HD) + g * HD;
    const unsigned short* vbase = vt + (size_t)((b * 4 + g) * HD) * TT;
    int ko[4], vo[4];
#pragma unroll
    for (int i = 0; i < 4; ++i) {
        int c = (i * 4 + w) * 64 + lane;
        int kt_ = c >> 4, kc = c & 15;
        ko[i] = kt_ * (HKK * HD) + ((kc ^ (kt_ & 7)) << 3);
        int dv = c >> 3, vc = c & 7;
        vo[i] = dv * TT + ((vc ^ (dv & 7)) << 3);
    }

#define STAGE(cb, jj) do {                                                   \
    short* Kd = SM + (cb) * 16384;                                           \
    short* Vd = Kd + 8192;                                                   \
    _Pragma("unroll")                                                        \
    for (int i_ = 0; i_ < 4; ++i_) {                                         \
        int blk_ = (i_ * 4 + w) * 512;                                       \
        __builtin_amdgcn_global_load_lds(                                    \
            GLOBAL_AS(kbase + (size_t)(jj) * 64 * (HKK * HD) + ko[i_]),      \
            LDS_AS(Kd + blk_), 16, 0, 0);                                    \
        __builtin_amdgcn_global_load_lds(                                    \
            GLOBAL_AS(vbase + (size_t)(jj) * 64 + vo[i_]),                   \
            LDS_AS(Vd + blk_), 16, 0, 0);                                    \
    }                                                                        \
} while (0)

    STAGE(0, j0);
    __syncthreads();                      // implicit vmcnt(0): buf0 ready

    int c = 0;
    for (int j = j0; j < jend; ++j) {
        if (j + 1 < jend) STAGE(c ^ 1, j + 1);   // async, in flight over compute

        if (j <= jdiag) {
            const short* Ks = SM + c * 16384;
            const short* Vs = Ks + 8192;
            // S^T = K·Q^T, two 32x32 tok-tiles.  A=K: row=tok=ct*32+l31.
            f32x16 sacc[2];
#pragma unroll
            for (int ct = 0; ct < 2; ++ct) {
#pragma unroll
                for (int e = 0; e < 16; ++e) sacc[ct][e] = 0.f;
#pragma unroll
                for (int ks = 0; ks < 8; ++ks) {
                    bf16x8 kf = *(const bf16x8*)&Ks[(ct * 32 + l31) * 128
                                                    + (((2 * ks + hi) << 3) ^ swz)];
                    sacc[ct] = __builtin_amdgcn_mfma_f32_32x32x16_bf16(kf, qf[ks], sacc[ct], 0, 0, 0);
                }
            }
            if (j == jdiag) {            // causal mask (diagonal tile only)
                int lim = l31 + 32 * (w & 1);   // tok_local > lim -> masked
#pragma unroll
                for (int ct = 0; ct < 2; ++ct)
#pragma unroll
                    for (int reg = 0; reg < 16; ++reg) {
                        int tok = ct * 32 + (reg & 3) + 8 * (reg >> 2) + 4 * hi;
                        if (tok > lim) sacc[ct][reg] = -1e30f;
                    }
            }
            // row max: tree (depth ~5) + 1 cross-half shfl
            float mx[8];
#pragma unroll
            for (int e = 0; e < 8; ++e)
                mx[e] = fmaxf(fmaxf(sacc[0][e], sacc[0][e + 8]),
                              fmaxf(sacc[1][e], sacc[1][e + 8]));
            float tmax = fmaxf(fmaxf(fmaxf(mx[0], mx[1]), fmaxf(mx[2], mx[3])),
                               fmaxf(fmaxf(mx[4], mx[5]), fmaxf(mx[6], mx[7])));
            tmax = fmaxf(tmax, __shfl_xor(tmax, 32));
            float m_new = fmaxf(m_i, tmax);
            float alpha = exp2f(m_i - m_new);
            m_i = m_new;

            // exp2 in place (sacc becomes P), sum as tree
#pragma unroll
            for (int ct = 0; ct < 2; ++ct)
#pragma unroll
                for (int e = 0; e < 16; ++e)
                    sacc[ct][e] = exp2f(sacc[ct][e] - m_new);
            float s8[8];
#pragma unroll
            for (int e = 0; e < 8; ++e)
                s8[e] = (sacc[0][e] + sacc[0][e + 8]) + (sacc[1][e] + sacc[1][e + 8]);
            float ps = ((s8[0] + s8[1]) + (s8[2] + s8[3]))
                     + ((s8[4] + s8[5]) + (s8[6] + s8[7]));
            l_i = l_i * alpha + ps;

            // rescale O (per-lane scalar alpha; o_acc qrow = l31)
#pragma unroll
            for (int t = 0; t < 4; ++t)
#pragma unroll
                for (int e = 0; e < 16; ++e) o_acc[t][e] *= alpha;

            // pack P to bf16 words: W[ct][bb][jj2] = pk(p[4bb+2jj2], p[4bb+2jj2+1])
            int W[2][4][2];
#pragma unroll
            for (int ct = 0; ct < 2; ++ct)
#pragma unroll
                for (int bb = 0; bb < 4; ++bb)
#pragma unroll
                    for (int jj2 = 0; jj2 < 2; ++jj2)
                        asm("v_cvt_pk_bf16_f32 %0, %1, %2"
                            : "=v"(W[ct][bb][jj2])
                            : "v"(sacc[ct][4 * bb + 2 * jj2]), "v"(sacc[ct][4 * bb + 2 * jj2 + 1]));

            // O^T += V^T·P^T : A=V from LDS, B=P in-register via permlane
#pragma unroll
            for (int ks = 0; ks < 4; ++ks) {
                int a0 = W[ks >> 1][2 * (ks & 1)][0];
                int a1 = W[ks >> 1][2 * (ks & 1)][1];
                int b0 = W[ks >> 1][2 * (ks & 1) + 1][0];
                int b1 = W[ks >> 1][2 * (ks & 1) + 1][1];
                asm("v_permlane32_swap_b32 %0, %1" : "+v"(a0), "+v"(b0));
                asm("v_permlane32_swap_b32 %0, %1" : "+v"(a1), "+v"(b1));
                i32x4 wv; wv[0] = a0; wv[1] = a1; wv[2] = b0; wv[3] = b1;
                bf16x8 pa = __builtin_bit_cast(bf16x8, wv);
#pragma unroll
                for (int t = 0; t < 4; ++t) {
                    bf16x8 vf = *(const bf16x8*)&Vs[(t * 32 + l31) * 64
                                                    + (((2 * ks + hi) << 3) ^ swz)];
                    o_acc[t] = __builtin_amdgcn_mfma_f32_32x32x16_bf16(vf, pa, o_acc[t], 0, 0, 0);
                }
            }
        }

        __syncthreads();   // implicit vmcnt(0)+lgkmcnt(0): next buf staged,
        c ^= 1;            // current buf's reads complete -> safe to overwrite
    }
#undef STAGE

    // finalize l: add the other 32-lane half's partial
    float lf = l_i + __shfl_xor(l_i, 32);
    float invl = 1.f / lf;

    if (hf == 2) {
        // Epilogue: stage O in LDS (128 rows x stride 136), coalesced stores.
        // o_acc[t][reg] = O[qrow=l31][d = t*32 + (reg&3) + 8*(reg>>2) + 4*hi]
        short* Es = SM;                    // 17408 <= 32768 shorts
#pragma unroll
        for (int t = 0; t < 4; ++t)
#pragma unroll
            for (int rg = 0; rg < 4; ++rg) {
                ushort4 o;
                o.x = f2bf(o_acc[t][rg * 4 + 0] * invl);
                o.y = f2bf(o_acc[t][rg * 4 + 1] * invl);
                o.z = f2bf(o_acc[t][rg * 4 + 2] * invl);
                o.w = f2bf(o_acc[t][rg * 4 + 3] * invl);
                *(ushort4*)&Es[(w * 32 + l31) * 136 + t * 32 + 8 * rg + 4 * hi] = o;
            }
        __syncthreads();
#pragma unroll
        for (int i = 0; i < 8; ++i) {
            int f = tid + i * 256;             // 0..2047
            int row = f >> 4, ch = f & 15;
            uint4 tv = *(const uint4*)&Es[row * 136 + ch * 8];
            *(uint4*)&y[(size_t)(b * TT + q0 + row) * CC + h * HD + ch * 8] = tv;
        }
    } else {
        // Split-chunk epilogue: normalized Ô (f32) + per-row s = l·2^m.
        const int pi = ((bh << 3) + (qi - 8)) * 2 + hf;
        if (hi == 0) sb[pi * 128 + w * 32 + l31] = lf * exp2f(m_i);
        float* pb = po + (size_t)pi * 16384;
#pragma unroll
        for (int t = 0; t < 4; ++t)
#pragma unroll
            for (int rg = 0; rg < 4; ++rg) {
                float4 o;
                o.x = o_acc[t][rg * 4 + 0] * invl;
                o.y = o_acc[t][rg * 4 + 1] * invl;
                o.z = o_acc[t][rg * 4 + 2] * invl;
                o.w = o_acc[t][rg * 4 + 3] * invl;
                *(float4*)&pb[(w * 32 + l31) * 128 + t * 32 + 8 * rg + 4 * hi] = o;
            }
    }
}

// ---------------------------------------------------------------------------
// Merge the two KV-half partials of split tiles (qi 8..15):
//   O = (s0·Ô0 + s1·Ô1)/(s0+s1),  then bf16 -> y.
// ---------------------------------------------------------------------------
__global__ __launch_bounds__(256) void combine_kernel(
    const float* __restrict__ po, const float* __restrict__ sb,
    unsigned short* __restrict__ y)
{
    const int bh = blockIdx.x;             // 0..31
    const int b = bh >> 4, h = bh & 15;
    const int qi = 8 + blockIdx.y;         // 8..15
    const int p0 = ((bh << 3) + (qi - 8)) * 2;
    const int t = threadIdx.x;
    const int row = t >> 1, d0 = (t & 1) * 64;
    float s0 = sb[p0 * 128 + row];
    float s1 = sb[(p0 + 1) * 128 + row];
    float w0 = s0 / (s0 + s1);
    float w1 = 1.f - w0;
    const float* a = &po[(size_t)p0 * 16384 + row * 128 + d0];
    const float* c = &po[(size_t)(p0 + 1) * 16384 + row * 128 + d0];
    unsigned short* yr = &y[(size_t)(b * TT + qi * 128 + row) * CC + h * HD + d0];
#pragma unroll
    for (int i = 0; i < 64; i += 4) {
        float4 xa = *(const float4*)&a[i];
        float4 xc = *(const float4*)&c[i];
        ushort4 o;
        o.x = f2bf(w0 * xa.x + w1 * xc.x);
        o.y = f2bf(w0 * xa.y + w1 * xc.y);
        o.z = f2bf(w0 * xa.z + w1 * xc.z);
        o.w = f2bf(w0 * xa.w + w1 * xc.w);
        *(ushort4*)&yr[i] = o;
    }
}

// ---------------------------------------------------------------------------
extern "C" void kernel_launch(void* const* d_in, const int* in_sizes, int n_in,
                              void* d_out, int out_size, void* d_ws, size_t ws_size,
                              hipStream_t stream) {
    const float* x    = (const float*)d_in[0];
    const float* cosb = (const float*)d_in[1];
    const float* sinb = (const float*)d_in[2];
    const float* Wq   = (const float*)d_in[3];
    const float* bq   = (const float*)d_in[4];
    const float* Wk   = (const float*)d_in[5];
    const float* bk   = (const float*)d_in[6];
    const float* Wv   = (const float*)d_in[7];
    const float* bv   = (const float*)d_in[8];
    const float* Wo   = (const float*)d_in[9];
    float* out = (float*)d_out;

    // workspace (all bf16 as ushort):
    // xb[4096*2048] Wt[3072*2048] Wot[2048*2048] qb[4096*2048]
    // kb[4096*512] vb[4096*512] vtb[1024*2048] yb[4096*2048]  = 83.9 MB
    unsigned short* xb  = (unsigned short*)d_ws;
    unsigned short* Wt  = xb  + (size_t)MM * CC;
    unsigned short* Wot = Wt  + (size_t)3072 * 2048;
    unsigned short* qb  = Wot + (size_t)2048 * 2048;
    unsigned short* kb  = qb  + (size_t)MM * CC;
    unsigned short* vb  = kb  + (size_t)MM * (HKK * HD);
    unsigned short* vtb = vb  + (size_t)MM * (HKK * HD);
    unsigned short* ybf = vtb + (size_t)BB * HKK * HD * TT;

    // Scratch aliases for the split-KV flash path (no new workspace):
    //  - po: 512 partial tiles x 128x128 f32 = 33.55 MB == d_out size exactly
    //        (d_out is dead until out_gemm overwrites every element).
    //  - sb: 512x128 f32 row-scalars s = l*2^m, over dead xb (dead after qkv).
    float* po = (float*)d_out;
    float* sbuf = (float*)xb;

    cast_x_kernel<<<dim3((MM * CC) / 2048), 256, 0, stream>>>(x, xb);
    wtrans_kernel<<<dim3(32, 32, 4), 256, 0, stream>>>(Wq, Wk, Wv, Wo, Wt, Wot);
    qkv_gemm_mfma<<<dim3(3072 / 128, MM / 128), 256, 0, stream>>>(
        xb, Wt, bq, bk, bv, cosb, sinb, qb, kb, vb);
    vtrans_kernel<<<dim3(TT / 64, HD / 64, BB * HKK), 256, 0, stream>>>(vb, vtb);
    flash_mfma<<<dim3(BB * HH, 24), 256, 0, stream>>>(qb, kb, vtb, ybf, po, sbuf);
    combine_kernel<<<dim3(BB * HH, 8), 256, 0, stream>>>(po, sbuf, ybf);
    out_gemm_mfma<<<dim3(CC / 128, MM / 128), 256, 0, stream>>>(ybf, Wot, out);
}

// Round 6
// 312.709 us; speedup vs baseline: 1.2656x; 1.0171x over previous
//
#include <hip/hip_runtime.h>
#include <math.h>

// Problem constants
#define BB 2
#define TT 2048
#define CC 2048
#define HH 16
#define HKK 4
#define HD 128
#define MM (BB*TT)          // 4096 rows

typedef short bf16x8 __attribute__((ext_vector_type(8)));
typedef float f32x4 __attribute__((ext_vector_type(4)));
typedef float f32x16 __attribute__((ext_vector_type(16)));
typedef int   i32x4 __attribute__((ext_vector_type(4)));

#define GLOBAL_AS(p) ((const __attribute__((address_space(1))) void*)(p))
#define LDS_AS(p)    ((__attribute__((address_space(3))) void*)(p))

__device__ __forceinline__ unsigned short f2bf(float f) {
    unsigned u = __float_as_uint(f);
    u += 0x7fff + ((u >> 16) & 1);          // round-to-nearest-even
    return (unsigned short)(u >> 16);
}
__device__ __forceinline__ float bf2f(unsigned short h) {
    return __uint_as_float(((unsigned)h) << 16);
}

// softmax scale 1/sqrt(128) * log2(e), folded into q at projection time
#define QSCALE (0.08838834764831845f * 1.44269504088896340736f)

// ---------------------------------------------------------------------------
// Fused prep: z=0..3 weight transpose+cast (W[K][N] f32 -> Wt[N][K] bf16),
// z=4..7 x cast (f32 -> bf16, 8 elem/thread).  One launch instead of two.
// ---------------------------------------------------------------------------
__global__ __launch_bounds__(256) void prep_kernel(
    const float* __restrict__ x, const float* __restrict__ Wq,
    const float* __restrict__ Wk, const float* __restrict__ Wv,
    const float* __restrict__ Wo, unsigned short* __restrict__ xb,
    unsigned short* __restrict__ Wt, unsigned short* __restrict__ Wot)
{
    __shared__ float tile[64][65];
    int z = blockIdx.z;
    if (z >= 4) {                          // cast path
        int bid = (z - 4) * 1024 + blockIdx.y * 32 + blockIdx.x;
        size_t i = ((size_t)bid * 256 + threadIdx.x) * 8;
        float4 a = *(const float4*)&x[i];
        float4 b = *(const float4*)&x[i + 4];
        uint4 r;
        r.x = f2bf(a.x) | ((unsigned)f2bf(a.y) << 16);
        r.y = f2bf(a.z) | ((unsigned)f2bf(a.w) << 16);
        r.z = f2bf(b.x) | ((unsigned)f2bf(b.y) << 16);
        r.w = f2bf(b.z) | ((unsigned)f2bf(b.w) << 16);
        *(uint4*)&xb[i] = r;
        return;
    }
    const float* src; unsigned short* dst; int ldW, nmax, noff;
    if (z == 0)      { src = Wq; dst = Wt;  ldW = 2048; nmax = 2048; noff = 0; }
    else if (z == 1) { src = Wk; dst = Wt;  ldW = 512;  nmax = 512;  noff = 2048; }
    else if (z == 2) { src = Wv; dst = Wt;  ldW = 512;  nmax = 512;  noff = 2560; }
    else             { src = Wo; dst = Wot; ldW = 2048; nmax = 2048; noff = 0; }
    int n0 = blockIdx.y * 64;
    if (n0 >= nmax) return;
    int k0 = blockIdx.x * 64;
    int tx = threadIdx.x & 15, ty = threadIdx.x >> 4;
#pragma unroll
    for (int i = 0; i < 4; ++i) {
        int r = ty + i * 16;
        float4 v4 = *(const float4*)&src[(size_t)(k0 + r) * ldW + n0 + tx * 4];
        tile[r][tx * 4 + 0] = v4.x;
        tile[r][tx * 4 + 1] = v4.y;
        tile[r][tx * 4 + 2] = v4.z;
        tile[r][tx * 4 + 3] = v4.w;
    }
    __syncthreads();
#pragma unroll
    for (int i = 0; i < 4; ++i) {
        int r = ty + i * 16;     // n-local
        int c = tx * 4;          // k-local
        ushort4 o;
        o.x = f2bf(tile[c + 0][r]);
        o.y = f2bf(tile[c + 1][r]);
        o.z = f2bf(tile[c + 2][r]);
        o.w = f2bf(tile[c + 3][r]);
        *(ushort4*)&dst[(size_t)(noff + n0 + r) * 2048 + k0 + c] = o;
    }
}

// ---------------------------------------------------------------------------
// MFMA GEMM core 128x128x64, 4 waves, 16x16x32 bf16, global_load_lds staging,
// XOR-swizzled k-chunks.  mrow/nrow give each wave's 4 m/n tile bases.
// ---------------------------------------------------------------------------
__device__ __forceinline__ void gemm_core_128x128x64(
    const unsigned short* __restrict__ A, const unsigned short* __restrict__ B,
    short* As, short* Bs, int m0, int n0,
    const int* mrow, const int* nrow, f32x4 (&acc)[4][4])
{
    const int tid = threadIdx.x;
    const int lane = tid & 63;
    const int w = tid >> 6;
    const int lm = lane & 15;
    const int q8 = lane >> 4;
    const int lrow = lane >> 3;            // 0..7 within an instr's 8 rows
    const int lchunk = lane & 7;           // lane's LDS chunk slot

    for (int kt = 0; kt < CC; kt += 64) {
        __syncthreads();                   // prev iter frag reads complete
#pragma unroll
        for (int jj = 0; jj < 4; ++jj) {
            int rA = w * 32 + jj * 8 + lrow;
            int cA = ((lchunk ^ (rA & 7)) << 3);
            __builtin_amdgcn_global_load_lds(
                GLOBAL_AS(&A[(size_t)(m0 + rA) * CC + kt + cA]),
                LDS_AS(&As[(w * 32 + jj * 8) * 64]), 16, 0, 0);
            __builtin_amdgcn_global_load_lds(
                GLOBAL_AS(&B[(size_t)(n0 + rA) * CC + kt + cA]),
                LDS_AS(&Bs[(w * 32 + jj * 8) * 64]), 16, 0, 0);
        }
        __syncthreads();                   // vmcnt drained -> tiles visible
#pragma unroll
        for (int ksi = 0; ksi < 2; ++ksi) {
            bf16x8 af[4], bfr[4];
#pragma unroll
            for (int i = 0; i < 4; ++i) {
                int xo = (((ksi * 4 + q8) ^ (lm & 7)) << 3);
                af[i]  = *(const bf16x8*)&As[(mrow[i] + lm) * 64 + xo];
                bfr[i] = *(const bf16x8*)&Bs[(nrow[i] + lm) * 64 + xo];
            }
#pragma unroll
            for (int im = 0; im < 4; ++im)
#pragma unroll
                for (int in = 0; in < 4; ++in)
                    acc[im][in] = __builtin_amdgcn_mfma_f32_16x16x32_bf16(af[im], bfr[in], acc[im][in], 0, 0, 0);
        }
    }
}

// ---------------------------------------------------------------------------
// QKV GEMM with fused bias + RoPE + q-scale.  Each 128-col block is exactly
// one head (HD=128).  Wave n-tiles remapped to {w1*32+(in&1)*16+(in>>1)*64}
// so d and d^64 are in the SAME lane at in^2 -> in-register RoPE.
// ---------------------------------------------------------------------------
__global__ __launch_bounds__(256, 3) void qkv_gemm_mfma(
    const unsigned short* __restrict__ xb, const unsigned short* __restrict__ Wt,
    const float* __restrict__ bq, const float* __restrict__ bk, const float* __restrict__ bv,
    const float* __restrict__ cosb, const float* __restrict__ sinb,
    unsigned short* __restrict__ q, unsigned short* __restrict__ k, unsigned short* __restrict__ v)
{
    __shared__ __attribute__((aligned(16))) short As[128 * 64];
    __shared__ __attribute__((aligned(16))) short Bs[128 * 64];
    const int lane = threadIdx.x & 63;
    const int w = threadIdx.x >> 6;
    const int w1 = w >> 1;
    const int m0 = blockIdx.y * 128;
    const int n0 = blockIdx.x * 128;
    const int lm = lane & 15;
    const int q8 = lane >> 4;

    int mrow[4], nrow[4];
#pragma unroll
    for (int i = 0; i < 4; ++i) {
        mrow[i] = (w & 1) * 64 + i * 16;
        nrow[i] = w1 * 32 + (i & 1) * 16 + (i >> 1) * 64;   // d and d^64 at in^2
    }

    f32x4 acc[4][4];
#pragma unroll
    for (int im = 0; im < 4; ++im)
#pragma unroll
        for (int in = 0; in < 4; ++in) acc[im][in] = {0.f, 0.f, 0.f, 0.f};

    gemm_core_128x128x64(xb, Wt, As, Bs, m0, n0, mrow, nrow, acc);

    unsigned short* dst; const float* bias; int ldD, off, mode;
    if (n0 < 2048)      { dst = q; bias = bq; ldD = 2048; off = n0;        mode = 0; }
    else if (n0 < 2560) { dst = k; bias = bk; ldD = 512;  off = n0 - 2048; mode = 1; }
    else                { dst = v; bias = bv; ldD = 512;  off = n0 - 2560; mode = 2; }

    float bv_[4];
#pragma unroll
    for (int in = 0; in < 4; ++in) bv_[in] = bias[off + nrow[in] + lm];

#pragma unroll
    for (int im = 0; im < 4; ++im) {
        int rowbase = m0 + mrow[im] + q8 * 4;
        float t[4][4];                      // [in][r], biased pre-rope values
#pragma unroll
        for (int in = 0; in < 4; ++in)
#pragma unroll
            for (int r = 0; r < 4; ++r) t[in][r] = acc[im][in][r] + bv_[in];
        if (mode < 2) {                     // rope (q and k)
#pragma unroll
            for (int in = 0; in < 4; ++in) {
                int d = nrow[in] + lm;
                float sgn = (in < 2) ? -1.f : 1.f;   // d<64 <=> in<2
#pragma unroll
                for (int r = 0; r < 4; ++r) {
                    int row = rowbase + r;
                    float c = cosb[row * HD + d];
                    float s = sinb[row * HD + d];
                    float o = c * t[in][r] + sgn * s * t[in ^ 2][r];
                    if (mode == 0) o *= QSCALE;
                    dst[(size_t)row * ldD + off + d] = f2bf(o);
                }
            }
        } else {                            // v: bias only
#pragma unroll
            for (int in = 0; in < 4; ++in)
#pragma unroll
                for (int r = 0; r < 4; ++r)
                    dst[(size_t)(rowbase + r) * ldD + off + nrow[in] + lm] = f2bf(t[in][r]);
        }
    }
}

__global__ __launch_bounds__(256, 3) void out_gemm_mfma(
    const unsigned short* __restrict__ yb, const unsigned short* __restrict__ Wot,
    float* __restrict__ Cout)
{
    __shared__ __attribute__((aligned(16))) short As[128 * 64];
    __shared__ __attribute__((aligned(16))) short Bs[128 * 64];
    const int lane = threadIdx.x & 63;
    const int w = threadIdx.x >> 6;
    const int m0 = blockIdx.y * 128;
    const int n0 = blockIdx.x * 128;
    const int lm = lane & 15;
    const int q8 = lane >> 4;

    int mrow[4], nrow[4];
#pragma unroll
    for (int i = 0; i < 4; ++i) {
        mrow[i] = (w & 1) * 64 + i * 16;
        nrow[i] = (w >> 1) * 64 + i * 16;
    }

    f32x4 acc[4][4];
#pragma unroll
    for (int im = 0; im < 4; ++im)
#pragma unroll
        for (int in = 0; in < 4; ++in) acc[im][in] = {0.f, 0.f, 0.f, 0.f};

    gemm_core_128x128x64(yb, Wot, As, Bs, m0, n0, mrow, nrow, acc);

#pragma unroll
    for (int im = 0; im < 4; ++im)
#pragma unroll
        for (int in = 0; in < 4; ++in)
#pragma unroll
            for (int r = 0; r < 4; ++r) {
                int row = m0 + mrow[im] + q8 * 4 + r;
                Cout[(size_t)row * CC + n0 + nrow[in] + lm] = acc[im][in][r];
            }
}

// ---------------------------------------------------------------------------
// V transpose: v[b][t][g*128+d] bf16 -> vt[(b*4+g)*128+d][t] bf16
// ---------------------------------------------------------------------------
__global__ __launch_bounds__(256) void vtrans_kernel(
    const unsigned short* __restrict__ v, unsigned short* __restrict__ vt)
{
    __shared__ unsigned short tile[64][68];
    int bg = blockIdx.z;           // b*4+g
    int b = bg >> 2, g = bg & 3;
    int t0 = blockIdx.x * 64;
    int d0 = blockIdx.y * 64;
    int tx = threadIdx.x & 15, ty = threadIdx.x >> 4;
#pragma unroll
    for (int i = 0; i < 4; ++i) {
        int r = ty + i * 16;
        ushort4 v4 = *(const ushort4*)&v[(size_t)(b * TT + t0 + r) * (HKK * HD) + g * HD + d0 + tx * 4];
        tile[r][tx * 4 + 0] = v4.x;
        tile[r][tx * 4 + 1] = v4.y;
        tile[r][tx * 4 + 2] = v4.z;
        tile[r][tx * 4 + 3] = v4.w;
    }
    __syncthreads();
#pragma unroll
    for (int i = 0; i < 4; ++i) {
        int r = ty + i * 16;   // d-local
        int c = tx * 4;        // t-local
        ushort4 o;
        o.x = tile[c + 0][r];
        o.y = tile[c + 1][r];
        o.z = tile[c + 2][r];
        o.w = tile[c + 3][r];
        *(ushort4*)&vt[(size_t)(bg * HD + d0 + r) * TT + t0 + c] = o;
    }
}

// ---------------------------------------------------------------------------
// Work-item table: 24 items per (b,h).  qi 0..7 unsplit (hf=2); qi 8..15
// split in two KV halves (hf=0/1).  Dispatch tiers (yb 0-7, 8-15, 16-23):
// with 3 blocks/CU resident, CU c runs the triple {t, t+8, t+16} which sums
// to exactly 34 iter-units for every t -> balanced makespan.
// ---------------------------------------------------------------------------
static __device__ const signed char QI_T[24] = {
    15, 7, 14, 14, 13, 6, 12, 11,
    15, 13, 12, 10, 10, 9, 11, 5,
    0, 1, 2, 3, 8, 4, 8, 9
};
static __device__ const signed char HF_T[24] = {
    0, 2, 0, 1, 1, 2, 1, 1,
    1, 0, 0, 0, 1, 0, 0, 2,
    2, 2, 2, 2, 0, 2, 1, 1
};

// ---------------------------------------------------------------------------
// MFMA flash attention v6: 32x32x16 MFMAs, 256 threads (4 waves), BR=128,
// BC=64.  r5 was residency-bound: 65536 B LDS -> 2 blocks/CU but measured
// 15.5% occupancy (~1.25 blocks); reg ceiling (168/wave) allows 12 waves/CU.
// Change: V is SINGLE-buffered (staged for the CURRENT iter at iter top,
// waited via counted s_waitcnt vmcnt(4) + raw s_barrier before PV — QK
// hides the V flight).  K stays double-buffered.  LDS 64->48 KB ->
// 3 blocks/CU = 12 waves/CU, matching the reg ceiling and the 3-resident
// tier table design.  launch_bounds(256,3) (cap 170 regs; usage ~165 after
// moving the W-pack into the PV loop).  Barriers are OUTSIDE the
// wave-divergent j<=jdiag guard (deadlock hazard).  Last-iter K prefetch
// clamps its address so the vmcnt count stays constant at 4.
// PV is O^T = V^T·P^T (qrow = lane&31); P built in-register via
// v_cvt_pk_bf16_f32 + v_permlane32_swap_b32.  Split chunks write normalized
// partials to po/sb; combine_kernel merges.
// ---------------------------------------------------------------------------
__global__ __launch_bounds__(256, 3) void flash_mfma(
    const unsigned short* __restrict__ q, const unsigned short* __restrict__ k,
    const unsigned short* __restrict__ vt, unsigned short* __restrict__ y,
    float* __restrict__ po, float* __restrict__ sb)
{
    // K buf c at SM + c*8192 (64x128 each) | Vs single at SM+16384 (128x64)
    // total 24576 shorts = 49152 B.  Epilogue Es (128x136=17408) reuses SM.
    __shared__ __attribute__((aligned(16))) short SM[24576];
    short* Vs = SM + 16384;

    const int tid = threadIdx.x;
    const int lane = tid & 63;
    const int w = tid >> 6;               // 0..3
    const int l31 = lane & 31;
    const int hi = lane >> 5;
    const int swz = (l31 & 7) << 3;       // read-side XOR (shorts)
    const int bh = blockIdx.x;            // 0..31
    const int b = bh >> 4, h = bh & 15, g = h >> 2;
    const int yb_ = blockIdx.y;           // 0..23
    const int qi = QI_T[yb_];
    const int hf = HF_T[yb_];             // 0/1 = split half, 2 = unsplit
    const int q0 = qi * 128;
    const int jdiag = 2 * qi + (w >> 1);  // this wave's diagonal tile
    int j0, jend;
    if (hf == 2)      { j0 = 0;      jend = 2 * qi + 2; }
    else if (hf == 0) { j0 = 0;      jend = qi + 1; }
    else              { j0 = qi + 1; jend = 2 * qi + 2; }

    // Q fragments: B-operand of S^T = K·Q^T. col=qrow=l31, k=ks*16+hi*8+e
    bf16x8 qf[8];
#pragma unroll
    for (int ks = 0; ks < 8; ++ks)
        qf[ks] = *(const bf16x8*)&q[(size_t)(b * TT + q0 + w * 32 + l31) * CC
                                    + h * HD + ks * 16 + hi * 8];

    f32x16 o_acc[4];
#pragma unroll
    for (int t = 0; t < 4; ++t)
#pragma unroll
        for (int e = 0; e < 16; ++e) o_acc[t][e] = 0.f;
    float m_i = -1e30f;                   // per-lane running max (exp2 domain)
    float l_i = 0.f;                      // per-lane partial row sum

    // Staging: 1024 K-chunks + 1024 V-chunks (16B) over 256 threads (4 each).
    // Chunk c = (i*4+w)*64 + lane; K: tok=c>>4, cc=c&15; V: d=c>>3, cc=c&7.
    // Source address carries the read-side swizzle (chunk ^= row&7); LDS
    // dest stays linear (rule #21).
    const unsigned short* kbase = k + (size_t)(b * TT) * (HKK * HD) + g * HD;
    const unsigned short* vbase = vt + (size_t)((b * 4 + g) * HD) * TT;
    int ko[4], vo[4];
#pragma unroll
    for (int i = 0; i < 4; ++i) {
        int c = (i * 4 + w) * 64 + lane;
        int kt_ = c >> 4, kc = c & 15;
        ko[i] = kt_ * (HKK * HD) + ((kc ^ (kt_ & 7)) << 3);
        int dv = c >> 3, vc = c & 7;
        vo[i] = dv * TT + ((vc ^ (dv & 7)) << 3);
    }

#define STAGE_K(cb, jj) do {                                                 \
    short* Kd = SM + (cb) * 8192;                                            \
    _Pragma("unroll")                                                        \
    for (int i_ = 0; i_ < 4; ++i_)                                           \
        __builtin_amdgcn_global_load_lds(                                    \
            GLOBAL_AS(kbase + (size_t)(jj) * 64 * (HKK * HD) + ko[i_]),      \
            LDS_AS(Kd + (i_ * 4 + w) * 512), 16, 0, 0);                      \
} while (0)
#define STAGE_V(jj) do {                                                     \
    _Pragma("unroll")                                                        \
    for (int i_ = 0; i_ < 4; ++i_)                                           \
        __builtin_amdgcn_global_load_lds(                                    \
            GLOBAL_AS(vbase + (size_t)(jj) * 64 + vo[i_]),                   \
            LDS_AS(Vs + (i_ * 4 + w) * 512), 16, 0, 0);                      \
} while (0)

    STAGE_K(0, j0);
    __syncthreads();                      // K buf0 ready

    int c = 0;
    for (int j = j0; j < jend; ++j) {
        STAGE_V(j);                       // V for THIS iter (4 loads, oldest)
        int jn = (j + 1 < jend) ? j + 1 : j;   // clamp: constant vmcnt count
        STAGE_K(c ^ 1, jn);               // K for next iter (4 loads)

        f32x16 sacc[2];
        if (j <= jdiag) {
            const short* Ks = SM + c * 8192;
            // S^T = K·Q^T, two 32x32 tok-tiles.  A=K: row=tok=ct*32+l31.
#pragma unroll
            for (int ct = 0; ct < 2; ++ct) {
#pragma unroll
                for (int e = 0; e < 16; ++e) sacc[ct][e] = 0.f;
#pragma unroll
                for (int ks = 0; ks < 8; ++ks) {
                    bf16x8 kf = *(const bf16x8*)&Ks[(ct * 32 + l31) * 128
                                                    + (((2 * ks + hi) << 3) ^ swz)];
                    sacc[ct] = __builtin_amdgcn_mfma_f32_32x32x16_bf16(kf, qf[ks], sacc[ct], 0, 0, 0);
                }
            }
            if (j == jdiag) {            // causal mask (diagonal tile only)
                int lim = l31 + 32 * (w & 1);   // tok_local > lim -> masked
#pragma unroll
                for (int ct = 0; ct < 2; ++ct)
#pragma unroll
                    for (int reg = 0; reg < 16; ++reg) {
                        int tok = ct * 32 + (reg & 3) + 8 * (reg >> 2) + 4 * hi;
                        if (tok > lim) sacc[ct][reg] = -1e30f;
                    }
            }
            // row max: tree (depth ~5) + 1 cross-half shfl
            float mx[8];
#pragma unroll
            for (int e = 0; e < 8; ++e)
                mx[e] = fmaxf(fmaxf(sacc[0][e], sacc[0][e + 8]),
                              fmaxf(sacc[1][e], sacc[1][e + 8]));
            float tmax = fmaxf(fmaxf(fmaxf(mx[0], mx[1]), fmaxf(mx[2], mx[3])),
                               fmaxf(fmaxf(mx[4], mx[5]), fmaxf(mx[6], mx[7])));
            tmax = fmaxf(tmax, __shfl_xor(tmax, 32));
            float m_new = fmaxf(m_i, tmax);
            float alpha = exp2f(m_i - m_new);
            m_i = m_new;

            // exp2 in place (sacc becomes P), sum as tree
#pragma unroll
            for (int ct = 0; ct < 2; ++ct)
#pragma unroll
                for (int e = 0; e < 16; ++e)
                    sacc[ct][e] = exp2f(sacc[ct][e] - m_new);
            float s8[8];
#pragma unroll
            for (int e = 0; e < 8; ++e)
                s8[e] = (sacc[0][e] + sacc[0][e + 8]) + (sacc[1][e] + sacc[1][e + 8]);
            float ps = ((s8[0] + s8[1]) + (s8[2] + s8[3]))
                     + ((s8[4] + s8[5]) + (s8[6] + s8[7]));
            l_i = l_i * alpha + ps;

            // rescale O (per-lane scalar alpha; o_acc qrow = l31)
#pragma unroll
            for (int t = 0; t < 4; ++t)
#pragma unroll
                for (int e = 0; e < 16; ++e) o_acc[t][e] *= alpha;
        }

        // V for this iter arrived (only the 4 K loads may stay in flight);
        // barrier publishes all threads' V chunks.  ALL waves participate.
        asm volatile("s_waitcnt vmcnt(4)" ::: "memory");
        __builtin_amdgcn_sched_barrier(0);
        __builtin_amdgcn_s_barrier();
        __builtin_amdgcn_sched_barrier(0);

        if (j <= jdiag) {
            // O^T += V^T·P^T : A=V from LDS, B=P in-register via permlane.
            // Pack per-ks (keeps live W words minimal).
#pragma unroll
            for (int ks = 0; ks < 4; ++ks) {
                const int ct = ks >> 1, base = 8 * (ks & 1);
                int a0, a1, b0, b1;
                asm("v_cvt_pk_bf16_f32 %0, %1, %2" : "=v"(a0)
                    : "v"(sacc[ct][base + 0]), "v"(sacc[ct][base + 1]));
                asm("v_cvt_pk_bf16_f32 %0, %1, %2" : "=v"(a1)
                    : "v"(sacc[ct][base + 2]), "v"(sacc[ct][base + 3]));
                asm("v_cvt_pk_bf16_f32 %0, %1, %2" : "=v"(b0)
                    : "v"(sacc[ct][base + 4]), "v"(sacc[ct][base + 5]));
                asm("v_cvt_pk_bf16_f32 %0, %1, %2" : "=v"(b1)
                    : "v"(sacc[ct][base + 6]), "v"(sacc[ct][base + 7]));
                asm("v_permlane32_swap_b32 %0, %1" : "+v"(a0), "+v"(b0));
                asm("v_permlane32_swap_b32 %0, %1" : "+v"(a1), "+v"(b1));
                i32x4 wv; wv[0] = a0; wv[1] = a1; wv[2] = b0; wv[3] = b1;
                bf16x8 pa = __builtin_bit_cast(bf16x8, wv);
#pragma unroll
                for (int t = 0; t < 4; ++t) {
                    bf16x8 vf = *(const bf16x8*)&Vs[(t * 32 + l31) * 64
                                                    + (((2 * ks + hi) << 3) ^ swz)];
                    o_acc[t] = __builtin_amdgcn_mfma_f32_32x32x16_bf16(vf, pa, o_acc[t], 0, 0, 0);
                }
            }
        }

        __syncthreads();   // drains vmcnt(0): next K staged; PV reads done ->
        c ^= 1;            // safe to overwrite Vs and K[c^1] next iter
    }
#undef STAGE_K
#undef STAGE_V

    // finalize l: add the other 32-lane half's partial
    float lf = l_i + __shfl_xor(l_i, 32);
    float invl = 1.f / lf;

    if (hf == 2) {
        // Epilogue: stage O in LDS (128 rows x stride 136), coalesced stores.
        // o_acc[t][reg] = O[qrow=l31][d = t*32 + (reg&3) + 8*(reg>>2) + 4*hi]
        short* Es = SM;                    // 17408 <= 24576 shorts
#pragma unroll
        for (int t = 0; t < 4; ++t)
#pragma unroll
            for (int rg = 0; rg < 4; ++rg) {
                ushort4 o;
                o.x = f2bf(o_acc[t][rg * 4 + 0] * invl);
                o.y = f2bf(o_acc[t][rg * 4 + 1] * invl);
                o.z = f2bf(o_acc[t][rg * 4 + 2] * invl);
                o.w = f2bf(o_acc[t][rg * 4 + 3] * invl);
                *(ushort4*)&Es[(w * 32 + l31) * 136 + t * 32 + 8 * rg + 4 * hi] = o;
            }
        __syncthreads();
#pragma unroll
        for (int i = 0; i < 8; ++i) {
            int f = tid + i * 256;             // 0..2047
            int row = f >> 4, ch = f & 15;
            uint4 tv = *(const uint4*)&Es[row * 136 + ch * 8];
            *(uint4*)&y[(size_t)(b * TT + q0 + row) * CC + h * HD + ch * 8] = tv;
        }
    } else {
        // Split-chunk epilogue: normalized Ô (f32) + per-row s = l·2^m.
        const int pi = ((bh << 3) + (qi - 8)) * 2 + hf;
        if (hi == 0) sb[pi * 128 + w * 32 + l31] = lf * exp2f(m_i);
        float* pb = po + (size_t)pi * 16384;
#pragma unroll
        for (int t = 0; t < 4; ++t)
#pragma unroll
            for (int rg = 0; rg < 4; ++rg) {
                float4 o;
                o.x = o_acc[t][rg * 4 + 0] * invl;
                o.y = o_acc[t][rg * 4 + 1] * invl;
                o.z = o_acc[t][rg * 4 + 2] * invl;
                o.w = o_acc[t][rg * 4 + 3] * invl;
                *(float4*)&pb[(w * 32 + l31) * 128 + t * 32 + 8 * rg + 4 * hi] = o;
            }
    }
}

// ---------------------------------------------------------------------------
// Merge the two KV-half partials of split tiles (qi 8..15):
//   O = (s0·Ô0 + s1·Ô1)/(s0+s1),  then bf16 -> y.
// ---------------------------------------------------------------------------
__global__ __launch_bounds__(256) void combine_kernel(
    const float* __restrict__ po, const float* __restrict__ sb,
    unsigned short* __restrict__ y)
{
    const int bh = blockIdx.x;             // 0..31
    const int b = bh >> 4, h = bh & 15;
    const int qi = 8 + blockIdx.y;         // 8..15
    const int p0 = ((bh << 3) + (qi - 8)) * 2;
    const int t = threadIdx.x;
    const int row = t >> 1, d0 = (t & 1) * 64;
    float s0 = sb[p0 * 128 + row];
    float s1 = sb[(p0 + 1) * 128 + row];
    float w0 = s0 / (s0 + s1);
    float w1 = 1.f - w0;
    const float* a = &po[(size_t)p0 * 16384 + row * 128 + d0];
    const float* c = &po[(size_t)(p0 + 1) * 16384 + row * 128 + d0];
    unsigned short* yr = &y[(size_t)(b * TT + qi * 128 + row) * CC + h * HD + d0];
#pragma unroll
    for (int i = 0; i < 64; i += 4) {
        float4 xa = *(const float4*)&a[i];
        float4 xc = *(const float4*)&c[i];
        ushort4 o;
        o.x = f2bf(w0 * xa.x + w1 * xc.x);
        o.y = f2bf(w0 * xa.y + w1 * xc.y);
        o.z = f2bf(w0 * xa.z + w1 * xc.z);
        o.w = f2bf(w0 * xa.w + w1 * xc.w);
        *(ushort4*)&yr[i] = o;
    }
}

// ---------------------------------------------------------------------------
extern "C" void kernel_launch(void* const* d_in, const int* in_sizes, int n_in,
                              void* d_out, int out_size, void* d_ws, size_t ws_size,
                              hipStream_t stream) {
    const float* x    = (const float*)d_in[0];
    const float* cosb = (const float*)d_in[1];
    const float* sinb = (const float*)d_in[2];
    const float* Wq   = (const float*)d_in[3];
    const float* bq   = (const float*)d_in[4];
    const float* Wk   = (const float*)d_in[5];
    const float* bk   = (const float*)d_in[6];
    const float* Wv   = (const float*)d_in[7];
    const float* bv   = (const float*)d_in[8];
    const float* Wo   = (const float*)d_in[9];
    float* out = (float*)d_out;

    // workspace (all bf16 as ushort):
    // xb[4096*2048] Wt[3072*2048] Wot[2048*2048] qb[4096*2048]
    // kb[4096*512] vb[4096*512] vtb[1024*2048] yb[4096*2048]  = 83.9 MB
    unsigned short* xb  = (unsigned short*)d_ws;
    unsigned short* Wt  = xb  + (size_t)MM * CC;
    unsigned short* Wot = Wt  + (size_t)3072 * 2048;
    unsigned short* qb  = Wot + (size_t)2048 * 2048;
    unsigned short* kb  = qb  + (size_t)MM * CC;
    unsigned short* vb  = kb  + (size_t)MM * (HKK * HD);
    unsigned short* vtb = vb  + (size_t)MM * (HKK * HD);
    unsigned short* ybf = vtb + (size_t)BB * HKK * HD * TT;

    // Scratch aliases for the split-KV flash path (no new workspace):
    //  - po: 512 partial tiles x 128x128 f32 = 33.55 MB == d_out size exactly
    //        (d_out is dead until out_gemm overwrites every element).
    //  - sb: 512x128 f32 row-scalars s = l*2^m, over dead xb (dead after qkv).
    float* po = (float*)d_out;
    float* sbuf = (float*)xb;

    prep_kernel<<<dim3(32, 32, 8), 256, 0, stream>>>(x, Wq, Wk, Wv, Wo, xb, Wt, Wot);
    qkv_gemm_mfma<<<dim3(3072 / 128, MM / 128), 256, 0, stream>>>(
        xb, Wt, bq, bk, bv, cosb, sinb, qb, kb, vb);
    vtrans_kernel<<<dim3(TT / 64, HD / 64, BB * HKK), 256, 0, stream>>>(vb, vtb);
    flash_mfma<<<dim3(BB * HH, 24), 256, 0, stream>>>(qb, kb, vtb, ybf, po, sbuf);
    combine_kernel<<<dim3(BB * HH, 8), 256, 0, stream>>>(po, sbuf, ybf);
    out_gemm_mfma<<<dim3(CC / 128, MM / 128), 256, 0, stream>>>(ybf, Wot, out);
}